// Round 18
// baseline (256.687 us; speedup 1.0000x reference)
//
#include <hip/hip_runtime.h>
#include <hip/hip_fp16.h>
#include <math.h>
#include <stdint.h>

#define A_ANG 400
#define DDET  512
#define NVOL  256
#define CCH   32
#define KSZ   11
#define PI_F  3.14159265358979323846f

#define NCHUNK 8
#define APC (A_ANG / NCHUNK)   // 50 angles per block (25 pairs, odd count)

typedef _Float16 half8 __attribute__((ext_vector_type(8)));
typedef __fp16  fp16x2 __attribute__((ext_vector_type(2)));  // cvt_pkrtz ret type
typedef float   floatx4 __attribute__((ext_vector_type(4)));
typedef uint32_t u32x4a __attribute__((ext_vector_type(4), aligned(4)));

// ---------------------------------------------------------------------------
// K1: causal detector conv -> f16 CHANNEL-MAJOR y[a][c][d] (packed half2).
// Also zeroes vol (memset graph node folded in).  Unchanged from R17.
// ---------------------------------------------------------------------------
__global__ __launch_bounds__(256) void k_detconv(const float* __restrict__ x,
                                                 const float* __restrict__ wdet,
                                                 const float* __restrict__ bdet,
                                                 __half* __restrict__ y2h,
                                                 float* __restrict__ vol) {
  __shared__ float wl[CCH * KSZ];
  __shared__ float bl[CCH];
  int t = threadIdx.x;
  for (int e = t; e < CCH * KSZ; e += 256) wl[e] = wdet[e];
  if (t < CCH) bl[t] = bdet[t];
  __syncthreads();

  int idx = blockIdx.x * 256 + t;  // = a*8192 + c*256 + d2
  if (idx < NVOL * NVOL * CCH) vol[idx] = 0.0f;  // zero vol for atomics
  int d2 = idx & 255;
  int c = (idx >> 8) & 31;
  int a = idx >> 13;
  const float* xr = x + a * DDET;
  int d0 = 2 * d2;
  float acc0 = bl[c], acc1 = bl[c];
#pragma unroll
  for (int k = 0; k < KSZ; ++k) {
    float wv = wl[c * KSZ + k];
    int dd0 = d0 + k - (KSZ - 1);
    int dd1 = dd0 + 1;
    float xv0 = (dd0 >= 0) ? xr[dd0] : 0.0f;
    float xv1 = (dd1 >= 0) ? xr[dd1] : 0.0f;
    acc0 = fmaf(wv, xv0, acc0);
    acc1 = fmaf(wv, xv1, acc1);
  }
  __half2 hv = __floats2half2_rn(acc0, acc1);
  *reinterpret_cast<__half2*>(y2h + ((size_t)(a * CCH + c) * DDET + d0)) = hv;
}

// ---------------------------------------------------------------------------
// K2: backprojection v14 — v13 + NCHUNK 5->8 (2048 blocks = 8 blk/CU,
// 32 waves/CU = HW max).  R17 left no pipe above ~52% with 35% issue-idle
// at 37% occupancy; ring deletion freed LDS (17.4 KB -> 8 blocks fit), so
// the R13-era occupancy blocker (saturated LDS pipe) is gone.  APC=50 has
// an odd pair count: last iteration's B-slot is guarded (wave-uniform).
// ---------------------------------------------------------------------------
__global__ __launch_bounds__(256, 8) void k_backproj(const __half* __restrict__ y2h,
                                                     float* __restrict__ vol) {
  __shared__ float s_epi[16 * 257];  // epilogue transpose (16.4 KB)
  __shared__ float s_sin[APC];
  __shared__ float s_cos[APC];

  int t = threadIdx.x;
  int lane = t & 63;
  int w = t >> 6;        // wave id 0..3
  int h = lane >> 4;     // k-group 0..3: angle ga=h>>1, cell-half hh=h&1
  int r = lane & 15;     // A-row / B,D-col index

  int tile = blockIdx.x & 255;
  int chunk = blockIdx.x >> 8;   // 0..NCHUNK-1 (grid = 256*NCHUNK)
  int a0 = chunk * APC;

  for (int a = t; a < APC; a += 256) {
    float ph = ((float)(a0 + a) + 0.5f) * (PI_F / (float)A_ANG);
    float sv, cv;
    sincosf(ph, &sv, &cv);
    s_sin[a] = sv;
    s_cos[a] = cv;
  }

  int bi = tile >> 4, bj = tile & 15;
  int wi = w >> 1, wj = w & 1;   // wave-tile position (2x2 of 8x8)
  int hh = h & 1;
  int ga = h >> 1;
  float Xcw = 124.0f - (float)(bi * 16 + 8 * wi);        // 127.5-(base+3.5)
  float Ycw = (float)(bj * 16 + 8 * wj) - 124.0f;
  float Xlh = 127.5f - (float)(bi * 16 + 8 * wi + 4 * hh + (r >> 3));
  float Yl  = (float)(bj * 16 + 8 * wj + (r & 7)) - 127.5f;

  int bpaA = (((h & 2) | 0) * 16 + r) << 2;
  int bpaB = (((h & 2) | 1) * 16 + r) << 2;

  const uint32_t* y2a = (const uint32_t*)y2h + (size_t)a0 * 8192;
  // per-lane invariant part of the window address (u32 units)
  int choff = r * 256 + 4 * hh;

  floatx4 acc[4][2];
#pragma unroll
  for (int m = 0; m < 4; ++m)
#pragma unroll
    for (int n = 0; n < 2; ++n) acc[m][n] = (floatx4){0.f, 0.f, 0.f, 0.f};

  __syncthreads();  // sin/cos tables ready

  union bfrag { u32x4a u4; half8 v; };

  // load this lane's 2 B-fragments for pair k (angle k+ga) straight from L2
  auto loadPair = [&](int k, bfrag& b0, bfrag& b1) {
    int ak = k + ga;
    ak = (ak < APC) ? ak : (APC - 1);   // tail prefetch clamp (data unused)
    float sp = s_sin[ak], cp = s_cos[ak];
    float ucw = fmaf(Xcw, sp, fmaf(Ycw, cp, 255.5f));
    int ibw = ((int)floorf(ucw) - 7) & ~1;
    const uint32_t* p = y2a + ak * 8192 + choff + (ibw >> 1);
    b0.u4 = *(const u32x4a*)p;          // ch r,    cells ibw+8hh..+7
    b1.u4 = *(const u32x4a*)(p + 4096); // ch 16+r, same cells
  };

  auto computePair = [&](int k, bfrag b0, bfrag b1) {
    int ak = k + ga;                  // lane's packed angle
    float sp = s_sin[ak], cp = s_cos[ak];
    float ucw = fmaf(Xcw, sp, fmaf(Ycw, cp, 255.5f));
    int ibw = ((int)floorf(ucw) - 7) & ~1;   // identical to load-time value
    uint32_t lov[2], msgv[2];
    float us = fmaf(Xlh, sp, fmaf(Yl, cp, 255.5f));
#pragma unroll
    for (int cch = 0; cch < 2; ++cch) {
      float fl = floorf(us);
      float wf = us - fl;
      int e = (int)fl - ibw;           // provably [2,13]
      float w0 = 1.0f - wf;
      union { fp16x2 hv; uint32_t u; } p01;
      p01.hv = __builtin_amdgcn_cvt_pkrtz(w0, wf);   // (w0,w1)
      // 64-bit shift trick: (lo,hi) = p01 << (16*(e&1))
      uint64_t v64 = ((uint64_t)p01.u) << ((e & 1) << 4);
      lov[cch] = (uint32_t)v64;
      msgv[cch] = (uint32_t)(v64 >> 32) | ((uint32_t)(e >> 1) << 16);
      us = fmaf(-2.0f, sp, us);  // next owned row (i += 2)
    }
    __builtin_amdgcn_s_setprio(1);
#pragma unroll
    for (int m = 0; m < 4; ++m) {
      int bpa = (m < 2) ? bpaA : bpaB;
      uint32_t lom =
          (uint32_t)__builtin_amdgcn_ds_bpermute(bpa, (int)((m & 1) ? lov[1] : lov[0]));
      uint32_t mm =
          (uint32_t)__builtin_amdgcn_ds_bpermute(bpa, (int)((m & 1) ? msgv[1] : msgv[0]));
      int qm = (int)(mm >> 16) - 4 * hh;
      uint32_t him = mm & 0xFFFFu;
      union { uint32_t u[4]; half8 v; } af;
#pragma unroll
      for (int j2 = 0; j2 < 4; ++j2) {
        uint32_t rj = (qm == j2) ? lom : 0u;
        rj = (qm == j2 - 1) ? him : rj;
        af.u[j2] = rj;
      }
      acc[m][0] =
          __builtin_amdgcn_mfma_f32_16x16x32_f16(af.v, b0.v, acc[m][0], 0, 0, 0);
      acc[m][1] =
          __builtin_amdgcn_mfma_f32_16x16x32_f16(af.v, b1.v, acc[m][1], 0, 0, 0);
    }
    __builtin_amdgcn_s_setprio(0);
  };

  // 2-pair register pipeline; APC=50 -> 25 pairs, last iteration B-guarded.
  bfrag A0, A1, B0, B1;
  loadPair(0, A0, A1);
  loadPair(2, B0, B1);
  for (int k = 0; k < APC; k += 4) {
    computePair(k, A0, A1);
    loadPair(k + 4, A0, A1);
    if (k + 2 < APC) {
      computePair(k + 2, B0, B1);
      loadPair(k + 6, B0, B1);
    }
  }

  __syncthreads();  // all waves done accumulating before epilogue writes

  const float DPHI = PI_F / (float)A_ANG;
  size_t gbase = ((size_t)(bi * 16) * NVOL + (size_t)(bj * 16)) * CCH;
#pragma unroll
  for (int n = 0; n < 2; ++n) {
    if (n) __syncthreads();  // pass-0 reads done before overwrite
#pragma unroll
    for (int m = 0; m < 4; ++m)
#pragma unroll
      for (int jr = 0; jr < 4; ++jr) {
        int p = 4 * h + jr;
        int px = (8 * wi + 2 * m + (p >> 3)) * 16 + 8 * wj + (p & 7);
        s_epi[r * 257 + px] = acc[m][n][jr] * DPHI;
      }
    __syncthreads();
#pragma unroll
    for (int mm = 0; mm < 16; ++mm) {
      int f = mm * 256 + t;
      int c16 = f & 15;
      int p2 = f >> 4;  // pixel 0..255
      int jj = p2 & 15, ii = p2 >> 4;
      float v = s_epi[c16 * 257 + p2];
      atomicAdd(vol + gbase + ((size_t)ii * NVOL + jj) * CCH + 16 * n + c16, v);
    }
  }
}

// ---------------------------------------------------------------------------
// K3: 3x3 causal conv 32->32 + sigmoid, MFMA formulation (unchanged, R17).
// ---------------------------------------------------------------------------
__global__ __launch_bounds__(256) void k_conv1(const float* __restrict__ vol,
                                               const float* __restrict__ w1,
                                               const float* __restrict__ b1,
                                               float* __restrict__ out1) {
  __shared__ uint32_t wlds[9 * 2 * 256];  // 18KB: [p][n][lane*4+q] f16-pairs
  int t = threadIdx.x;
  for (int u = t; u < 9 * 2 * 256; u += 256) {
    int q = u & 3;
    int lane_s = (u >> 2) & 63;
    int blk = u >> 8;          // 0..17
    int p = blk >> 1, n = blk & 1;
    int hs = lane_s >> 4, rs = lane_s & 15;
    int oc = 16 * n + rs;
    int ci0 = 8 * hs + 2 * q;
    int di = p / 3, dj = p % 3;
    float a0 = w1[((oc * CCH + ci0) * 3 + di) * 3 + dj];
    float a1 = w1[((oc * CCH + ci0 + 1) * 3 + di) * 3 + dj];
    union { fp16x2 hv; uint32_t u32; } pk;
    pk.hv = __builtin_amdgcn_cvt_pkrtz(a0, a1);
    wlds[u] = pk.u32;
  }
  __syncthreads();

  int lane = t & 63;
  int w = t >> 6;
  int h = lane >> 4, r = lane & 15;
  int px0 = (blockIdx.x * 4 + w) * 16;  // 16-aligned -> single image row
  int i = px0 >> 8, j0 = px0 & 255;

  floatx4 acc[2];
  float bv0 = b1[r], bv1 = b1[16 + r];
  acc[0] = (floatx4){bv0, bv0, bv0, bv0};
  acc[1] = (floatx4){bv1, bv1, bv1, bv1};

#pragma unroll
  for (int p = 0; p < 9; ++p) {
    int di = p / 3, dj = p % 3;
    int ii = i + di - 2;
    if (ii >= 0) {                       // wave-uniform causal row skip
      int jrp = j0 + r + dj - 2;         // A-row r's source column
      int jc = max(jrp, 0);
      const float4* ap =
          (const float4*)(vol + ((size_t)(ii * NVOL + jc)) * CCH + 8 * h);
      float4 v0 = ap[0], v1 = ap[1];
      if (jrp < 0) {                     // zero-pad (only j0=0, r<2, dj<2)
        v0 = (float4){0.f, 0.f, 0.f, 0.f};
        v1 = (float4){0.f, 0.f, 0.f, 0.f};
      }
      union { uint32_t u[4]; half8 v; } af;
      union { fp16x2 hv; uint32_t u32; } c0, c1, c2, c3;
      c0.hv = __builtin_amdgcn_cvt_pkrtz(v0.x, v0.y);
      c1.hv = __builtin_amdgcn_cvt_pkrtz(v0.z, v0.w);
      c2.hv = __builtin_amdgcn_cvt_pkrtz(v1.x, v1.y);
      c3.hv = __builtin_amdgcn_cvt_pkrtz(v1.z, v1.w);
      af.u[0] = c0.u32; af.u[1] = c1.u32; af.u[2] = c2.u32; af.u[3] = c3.u32;
      half8 bf0 = *(const half8*)(wlds + (p * 2 + 0) * 256 + lane * 4);
      half8 bf1 = *(const half8*)(wlds + (p * 2 + 1) * 256 + lane * 4);
      acc[0] = __builtin_amdgcn_mfma_f32_16x16x32_f16(af.v, bf0, acc[0], 0, 0, 0);
      acc[1] = __builtin_amdgcn_mfma_f32_16x16x32_f16(af.v, bf1, acc[1], 0, 0, 0);
    }
  }

  // D: lane holds pixels px0+4h+jr, oc = 16n+r
#pragma unroll
  for (int n = 0; n < 2; ++n)
#pragma unroll
    for (int jr = 0; jr < 4; ++jr) {
      float s = 1.0f / (1.0f + expf(-acc[n][jr]));
      out1[(size_t)(px0 + 4 * h + jr) * CCH + 16 * n + r] = s;
    }
}

// ---------------------------------------------------------------------------
// K4: 3x3 causal conv 32->1 + sigmoid, coalesced lane mapping (unchanged).
// ---------------------------------------------------------------------------
__global__ __launch_bounds__(256) void k_conv2(const float* __restrict__ s1,
                                               const float* __restrict__ w2,
                                               const float* __restrict__ b2,
                                               float* __restrict__ out) {
  __shared__ float wl[9 * CCH];  // [p][ci]
  __shared__ float red[256];
  int t = threadIdx.x;
  for (int e = t; e < 9 * CCH; e += 256) {
    int ci = e & 31, p = e >> 5;
    int di = p / 3, dj = p % 3;
    wl[e] = w2[ci * 9 + di * 3 + dj];
  }
  __syncthreads();

  int px0 = blockIdx.x * 64;
  int pix = px0 + (t >> 2);        // coalesced: 4 consecutive lanes = 1 px
  int j = pix & 255, i = pix >> 8;
  int cg = (t & 3) * 8;            // this thread's 8 input channels

  float acc = 0.0f;
#pragma unroll
  for (int p = 0; p < 9; ++p) {
    int di = p / 3, dj = p % 3;
    int ii = i + di - 2, jj = j + dj - 2;
    if (ii >= 0 && jj >= 0) {
      const float4* ip4 =
          (const float4*)(s1 + ((size_t)(ii * NVOL + jj)) * CCH + cg);
      const float4* wv4 = (const float4*)(&wl[p * CCH + cg]);
      float4 v0 = ip4[0], v1 = ip4[1];
      float4 w0 = wv4[0], w1 = wv4[1];
      acc = fmaf(v0.x, w0.x, acc);
      acc = fmaf(v0.y, w0.y, acc);
      acc = fmaf(v0.z, w0.z, acc);
      acc = fmaf(v0.w, w0.w, acc);
      acc = fmaf(v1.x, w1.x, acc);
      acc = fmaf(v1.y, w1.y, acc);
      acc = fmaf(v1.z, w1.z, acc);
      acc = fmaf(v1.w, w1.w, acc);
    }
  }
  red[t] = acc;
  __syncthreads();
  if (t < 64) {
    float4 rv = *(const float4*)(&red[4 * t]);
    float s = rv.x + rv.y + rv.z + rv.w + b2[0];
    out[px0 + t] = 1.0f / (1.0f + expf(-s));
  }
}

// ---------------------------------------------------------------------------
extern "C" void kernel_launch(void* const* d_in, const int* in_sizes, int n_in,
                              void* d_out, int out_size, void* d_ws,
                              size_t ws_size, hipStream_t stream) {
  const float* x    = (const float*)d_in[0];  // [1,1,400,512]
  const float* wdet = (const float*)d_in[1];  // [32,1,1,11]
  const float* bdet = (const float*)d_in[2];  // [32]
  const float* w1   = (const float*)d_in[3];  // [32,32,3,3]
  const float* b1   = (const float*)d_in[4];  // [32]
  const float* w2   = (const float*)d_in[5];  // [1,32,3,3]
  const float* b2   = (const float*)d_in[6];  // [1]
  float* out = (float*)d_out;                 // [1,1,256,256]

  float* ws = (float*)d_ws;
  __half* y2h = (__half*)ws;                         // [400][32][512] f16 = 13.1 MB
  float* vol  = ws + (A_ANG * CCH * DDET) / 2;       // [256][256][32] f32 = 8.4 MB
  float* sig1 = vol + NVOL * NVOL * CCH;             // [256][256][32] f32 = 8.4 MB

  // detconv also zeroes vol (memset node folded in; 4 graph nodes total)
  k_detconv<<<dim3((A_ANG * CCH * DDET / 2) / 256), dim3(256), 0, stream>>>(
      x, wdet, bdet, y2h, vol);
  k_backproj<<<dim3(256 * NCHUNK), dim3(256), 0, stream>>>(y2h, vol);
  k_conv1<<<dim3(256 * 4), dim3(256), 0, stream>>>(vol, w1, b1, sig1);
  k_conv2<<<dim3(256 * 4), dim3(256), 0, stream>>>(sig1, w2, b2, out);
}

// Round 19
// 159.189 us; speedup vs baseline: 1.6125x; 1.6125x over previous
//
#include <hip/hip_runtime.h>
#include <hip/hip_fp16.h>
#include <math.h>
#include <stdint.h>

#define A_ANG 400
#define DDET  512
#define NVOL  256
#define CCH   32
#define KSZ   11
#define PI_F  3.14159265358979323846f

#define NCHUNK 8
#define APC (A_ANG / NCHUNK)   // 50 angles per block (25 pairs, odd count)

typedef _Float16 half8 __attribute__((ext_vector_type(8)));
typedef __fp16  fp16x2 __attribute__((ext_vector_type(2)));  // cvt_pkrtz ret type
typedef float   floatx4 __attribute__((ext_vector_type(4)));
typedef uint32_t u32x4a __attribute__((ext_vector_type(4), aligned(4)));

// ---------------------------------------------------------------------------
// K1: causal detector conv -> f16 CHANNEL-MAJOR y[a][c][d] (packed half2).
// Also zeroes vol (memset graph node folded in).  Unchanged from R17.
// ---------------------------------------------------------------------------
__global__ __launch_bounds__(256) void k_detconv(const float* __restrict__ x,
                                                 const float* __restrict__ wdet,
                                                 const float* __restrict__ bdet,
                                                 __half* __restrict__ y2h,
                                                 float* __restrict__ vol) {
  __shared__ float wl[CCH * KSZ];
  __shared__ float bl[CCH];
  int t = threadIdx.x;
  for (int e = t; e < CCH * KSZ; e += 256) wl[e] = wdet[e];
  if (t < CCH) bl[t] = bdet[t];
  __syncthreads();

  int idx = blockIdx.x * 256 + t;  // = a*8192 + c*256 + d2
  if (idx < NVOL * NVOL * CCH) vol[idx] = 0.0f;  // zero vol for atomics
  int d2 = idx & 255;
  int c = (idx >> 8) & 31;
  int a = idx >> 13;
  const float* xr = x + a * DDET;
  int d0 = 2 * d2;
  float acc0 = bl[c], acc1 = bl[c];
#pragma unroll
  for (int k = 0; k < KSZ; ++k) {
    float wv = wl[c * KSZ + k];
    int dd0 = d0 + k - (KSZ - 1);
    int dd1 = dd0 + 1;
    float xv0 = (dd0 >= 0) ? xr[dd0] : 0.0f;
    float xv1 = (dd1 >= 0) ? xr[dd1] : 0.0f;
    acc0 = fmaf(wv, xv0, acc0);
    acc1 = fmaf(wv, xv1, acc1);
  }
  __half2 hv = __floats2half2_rn(acc0, acc1);
  *reinterpret_cast<__half2*>(y2h + ((size_t)(a * CCH + c) * DDET + d0)) = hv;
}

// ---------------------------------------------------------------------------
// K2: backprojection v15 — NCHUNK=8 retry with launch_bounds(256,4).
// R18 post-mortem: (256,8) squeezed VGPR 40->32 -> scratch spill storm
// (463 MB phantom WRITE).  The occupancy theory was never tested.  v15
// keeps NCHUNK=8 (2048 blocks; LDS 16.9 KB allows 9 blk/CU) but restores
// the (256,4) budget that yields VGPR=40 — runtime residency can still
// reach 8 blk/CU since neither LDS nor VGPR(40) binds before 8.
// ---------------------------------------------------------------------------
__global__ __launch_bounds__(256, 4) void k_backproj(const __half* __restrict__ y2h,
                                                     float* __restrict__ vol) {
  __shared__ float s_epi[16 * 257];  // epilogue transpose (16.4 KB)
  __shared__ float s_sin[APC];
  __shared__ float s_cos[APC];

  int t = threadIdx.x;
  int lane = t & 63;
  int w = t >> 6;        // wave id 0..3
  int h = lane >> 4;     // k-group 0..3: angle ga=h>>1, cell-half hh=h&1
  int r = lane & 15;     // A-row / B,D-col index

  int tile = blockIdx.x & 255;
  int chunk = blockIdx.x >> 8;   // 0..NCHUNK-1 (grid = 256*NCHUNK)
  int a0 = chunk * APC;

  for (int a = t; a < APC; a += 256) {
    float ph = ((float)(a0 + a) + 0.5f) * (PI_F / (float)A_ANG);
    float sv, cv;
    sincosf(ph, &sv, &cv);
    s_sin[a] = sv;
    s_cos[a] = cv;
  }

  int bi = tile >> 4, bj = tile & 15;
  int wi = w >> 1, wj = w & 1;   // wave-tile position (2x2 of 8x8)
  int hh = h & 1;
  int ga = h >> 1;
  float Xcw = 124.0f - (float)(bi * 16 + 8 * wi);        // 127.5-(base+3.5)
  float Ycw = (float)(bj * 16 + 8 * wj) - 124.0f;
  float Xlh = 127.5f - (float)(bi * 16 + 8 * wi + 4 * hh + (r >> 3));
  float Yl  = (float)(bj * 16 + 8 * wj + (r & 7)) - 127.5f;

  int bpaA = (((h & 2) | 0) * 16 + r) << 2;
  int bpaB = (((h & 2) | 1) * 16 + r) << 2;

  const uint32_t* y2a = (const uint32_t*)y2h + (size_t)a0 * 8192;
  // per-lane invariant part of the window address (u32 units)
  int choff = r * 256 + 4 * hh;

  floatx4 acc[4][2];
#pragma unroll
  for (int m = 0; m < 4; ++m)
#pragma unroll
    for (int n = 0; n < 2; ++n) acc[m][n] = (floatx4){0.f, 0.f, 0.f, 0.f};

  __syncthreads();  // sin/cos tables ready

  union bfrag { u32x4a u4; half8 v; };

  // load this lane's 2 B-fragments for pair k (angle k+ga) straight from L2
  auto loadPair = [&](int k, bfrag& b0, bfrag& b1) {
    int ak = k + ga;
    ak = (ak < APC) ? ak : (APC - 1);   // tail prefetch clamp (data unused)
    float sp = s_sin[ak], cp = s_cos[ak];
    float ucw = fmaf(Xcw, sp, fmaf(Ycw, cp, 255.5f));
    int ibw = ((int)floorf(ucw) - 7) & ~1;
    const uint32_t* p = y2a + ak * 8192 + choff + (ibw >> 1);
    b0.u4 = *(const u32x4a*)p;          // ch r,    cells ibw+8hh..+7
    b1.u4 = *(const u32x4a*)(p + 4096); // ch 16+r, same cells
  };

  auto computePair = [&](int k, bfrag b0, bfrag b1) {
    int ak = k + ga;                  // lane's packed angle
    float sp = s_sin[ak], cp = s_cos[ak];
    float ucw = fmaf(Xcw, sp, fmaf(Ycw, cp, 255.5f));
    int ibw = ((int)floorf(ucw) - 7) & ~1;   // identical to load-time value
    uint32_t lov[2], msgv[2];
    float us = fmaf(Xlh, sp, fmaf(Yl, cp, 255.5f));
#pragma unroll
    for (int cch = 0; cch < 2; ++cch) {
      float fl = floorf(us);
      float wf = us - fl;
      int e = (int)fl - ibw;           // provably [2,13]
      float w0 = 1.0f - wf;
      union { fp16x2 hv; uint32_t u; } p01;
      p01.hv = __builtin_amdgcn_cvt_pkrtz(w0, wf);   // (w0,w1)
      // 64-bit shift trick: (lo,hi) = p01 << (16*(e&1))
      uint64_t v64 = ((uint64_t)p01.u) << ((e & 1) << 4);
      lov[cch] = (uint32_t)v64;
      msgv[cch] = (uint32_t)(v64 >> 32) | ((uint32_t)(e >> 1) << 16);
      us = fmaf(-2.0f, sp, us);  // next owned row (i += 2)
    }
    __builtin_amdgcn_s_setprio(1);
#pragma unroll
    for (int m = 0; m < 4; ++m) {
      int bpa = (m < 2) ? bpaA : bpaB;
      uint32_t lom =
          (uint32_t)__builtin_amdgcn_ds_bpermute(bpa, (int)((m & 1) ? lov[1] : lov[0]));
      uint32_t mm =
          (uint32_t)__builtin_amdgcn_ds_bpermute(bpa, (int)((m & 1) ? msgv[1] : msgv[0]));
      int qm = (int)(mm >> 16) - 4 * hh;
      uint32_t him = mm & 0xFFFFu;
      union { uint32_t u[4]; half8 v; } af;
#pragma unroll
      for (int j2 = 0; j2 < 4; ++j2) {
        uint32_t rj = (qm == j2) ? lom : 0u;
        rj = (qm == j2 - 1) ? him : rj;
        af.u[j2] = rj;
      }
      acc[m][0] =
          __builtin_amdgcn_mfma_f32_16x16x32_f16(af.v, b0.v, acc[m][0], 0, 0, 0);
      acc[m][1] =
          __builtin_amdgcn_mfma_f32_16x16x32_f16(af.v, b1.v, acc[m][1], 0, 0, 0);
    }
    __builtin_amdgcn_s_setprio(0);
  };

  // 2-pair register pipeline; APC=50 -> 25 pairs, last iteration B-guarded.
  bfrag A0, A1, B0, B1;
  loadPair(0, A0, A1);
  loadPair(2, B0, B1);
  for (int k = 0; k < APC; k += 4) {
    computePair(k, A0, A1);
    loadPair(k + 4, A0, A1);
    if (k + 2 < APC) {
      computePair(k + 2, B0, B1);
      loadPair(k + 6, B0, B1);
    }
  }

  __syncthreads();  // all waves done accumulating before epilogue writes

  const float DPHI = PI_F / (float)A_ANG;
  size_t gbase = ((size_t)(bi * 16) * NVOL + (size_t)(bj * 16)) * CCH;
#pragma unroll
  for (int n = 0; n < 2; ++n) {
    if (n) __syncthreads();  // pass-0 reads done before overwrite
#pragma unroll
    for (int m = 0; m < 4; ++m)
#pragma unroll
      for (int jr = 0; jr < 4; ++jr) {
        int p = 4 * h + jr;
        int px = (8 * wi + 2 * m + (p >> 3)) * 16 + 8 * wj + (p & 7);
        s_epi[r * 257 + px] = acc[m][n][jr] * DPHI;
      }
    __syncthreads();
#pragma unroll
    for (int mm = 0; mm < 16; ++mm) {
      int f = mm * 256 + t;
      int c16 = f & 15;
      int p2 = f >> 4;  // pixel 0..255
      int jj = p2 & 15, ii = p2 >> 4;
      float v = s_epi[c16 * 257 + p2];
      atomicAdd(vol + gbase + ((size_t)ii * NVOL + jj) * CCH + 16 * n + c16, v);
    }
  }
}

// ---------------------------------------------------------------------------
// K3: 3x3 causal conv 32->32 + sigmoid, MFMA formulation (unchanged, R17).
// ---------------------------------------------------------------------------
__global__ __launch_bounds__(256) void k_conv1(const float* __restrict__ vol,
                                               const float* __restrict__ w1,
                                               const float* __restrict__ b1,
                                               float* __restrict__ out1) {
  __shared__ uint32_t wlds[9 * 2 * 256];  // 18KB: [p][n][lane*4+q] f16-pairs
  int t = threadIdx.x;
  for (int u = t; u < 9 * 2 * 256; u += 256) {
    int q = u & 3;
    int lane_s = (u >> 2) & 63;
    int blk = u >> 8;          // 0..17
    int p = blk >> 1, n = blk & 1;
    int hs = lane_s >> 4, rs = lane_s & 15;
    int oc = 16 * n + rs;
    int ci0 = 8 * hs + 2 * q;
    int di = p / 3, dj = p % 3;
    float a0 = w1[((oc * CCH + ci0) * 3 + di) * 3 + dj];
    float a1 = w1[((oc * CCH + ci0 + 1) * 3 + di) * 3 + dj];
    union { fp16x2 hv; uint32_t u32; } pk;
    pk.hv = __builtin_amdgcn_cvt_pkrtz(a0, a1);
    wlds[u] = pk.u32;
  }
  __syncthreads();

  int lane = t & 63;
  int w = t >> 6;
  int h = lane >> 4, r = lane & 15;
  int px0 = (blockIdx.x * 4 + w) * 16;  // 16-aligned -> single image row
  int i = px0 >> 8, j0 = px0 & 255;

  floatx4 acc[2];
  float bv0 = b1[r], bv1 = b1[16 + r];
  acc[0] = (floatx4){bv0, bv0, bv0, bv0};
  acc[1] = (floatx4){bv1, bv1, bv1, bv1};

#pragma unroll
  for (int p = 0; p < 9; ++p) {
    int di = p / 3, dj = p % 3;
    int ii = i + di - 2;
    if (ii >= 0) {                       // wave-uniform causal row skip
      int jrp = j0 + r + dj - 2;         // A-row r's source column
      int jc = max(jrp, 0);
      const float4* ap =
          (const float4*)(vol + ((size_t)(ii * NVOL + jc)) * CCH + 8 * h);
      float4 v0 = ap[0], v1 = ap[1];
      if (jrp < 0) {                     // zero-pad (only j0=0, r<2, dj<2)
        v0 = (float4){0.f, 0.f, 0.f, 0.f};
        v1 = (float4){0.f, 0.f, 0.f, 0.f};
      }
      union { uint32_t u[4]; half8 v; } af;
      union { fp16x2 hv; uint32_t u32; } c0, c1, c2, c3;
      c0.hv = __builtin_amdgcn_cvt_pkrtz(v0.x, v0.y);
      c1.hv = __builtin_amdgcn_cvt_pkrtz(v0.z, v0.w);
      c2.hv = __builtin_amdgcn_cvt_pkrtz(v1.x, v1.y);
      c3.hv = __builtin_amdgcn_cvt_pkrtz(v1.z, v1.w);
      af.u[0] = c0.u32; af.u[1] = c1.u32; af.u[2] = c2.u32; af.u[3] = c3.u32;
      half8 bf0 = *(const half8*)(wlds + (p * 2 + 0) * 256 + lane * 4);
      half8 bf1 = *(const half8*)(wlds + (p * 2 + 1) * 256 + lane * 4);
      acc[0] = __builtin_amdgcn_mfma_f32_16x16x32_f16(af.v, bf0, acc[0], 0, 0, 0);
      acc[1] = __builtin_amdgcn_mfma_f32_16x16x32_f16(af.v, bf1, acc[1], 0, 0, 0);
    }
  }

  // D: lane holds pixels px0+4h+jr, oc = 16n+r
#pragma unroll
  for (int n = 0; n < 2; ++n)
#pragma unroll
    for (int jr = 0; jr < 4; ++jr) {
      float s = 1.0f / (1.0f + expf(-acc[n][jr]));
      out1[(size_t)(px0 + 4 * h + jr) * CCH + 16 * n + r] = s;
    }
}

// ---------------------------------------------------------------------------
// K4: 3x3 causal conv 32->1 + sigmoid, coalesced lane mapping (unchanged).
// ---------------------------------------------------------------------------
__global__ __launch_bounds__(256) void k_conv2(const float* __restrict__ s1,
                                               const float* __restrict__ w2,
                                               const float* __restrict__ b2,
                                               float* __restrict__ out) {
  __shared__ float wl[9 * CCH];  // [p][ci]
  __shared__ float red[256];
  int t = threadIdx.x;
  for (int e = t; e < 9 * CCH; e += 256) {
    int ci = e & 31, p = e >> 5;
    int di = p / 3, dj = p % 3;
    wl[e] = w2[ci * 9 + di * 3 + dj];
  }
  __syncthreads();

  int px0 = blockIdx.x * 64;
  int pix = px0 + (t >> 2);        // coalesced: 4 consecutive lanes = 1 px
  int j = pix & 255, i = pix >> 8;
  int cg = (t & 3) * 8;            // this thread's 8 input channels

  float acc = 0.0f;
#pragma unroll
  for (int p = 0; p < 9; ++p) {
    int di = p / 3, dj = p % 3;
    int ii = i + di - 2, jj = j + dj - 2;
    if (ii >= 0 && jj >= 0) {
      const float4* ip4 =
          (const float4*)(s1 + ((size_t)(ii * NVOL + jj)) * CCH + cg);
      const float4* wv4 = (const float4*)(&wl[p * CCH + cg]);
      float4 v0 = ip4[0], v1 = ip4[1];
      float4 w0 = wv4[0], w1 = wv4[1];
      acc = fmaf(v0.x, w0.x, acc);
      acc = fmaf(v0.y, w0.y, acc);
      acc = fmaf(v0.z, w0.z, acc);
      acc = fmaf(v0.w, w0.w, acc);
      acc = fmaf(v1.x, w1.x, acc);
      acc = fmaf(v1.y, w1.y, acc);
      acc = fmaf(v1.z, w1.z, acc);
      acc = fmaf(v1.w, w1.w, acc);
    }
  }
  red[t] = acc;
  __syncthreads();
  if (t < 64) {
    float4 rv = *(const float4*)(&red[4 * t]);
    float s = rv.x + rv.y + rv.z + rv.w + b2[0];
    out[px0 + t] = 1.0f / (1.0f + expf(-s));
  }
}

// ---------------------------------------------------------------------------
extern "C" void kernel_launch(void* const* d_in, const int* in_sizes, int n_in,
                              void* d_out, int out_size, void* d_ws,
                              size_t ws_size, hipStream_t stream) {
  const float* x    = (const float*)d_in[0];  // [1,1,400,512]
  const float* wdet = (const float*)d_in[1];  // [32,1,1,11]
  const float* bdet = (const float*)d_in[2];  // [32]
  const float* w1   = (const float*)d_in[3];  // [32,32,3,3]
  const float* b1   = (const float*)d_in[4];  // [32]
  const float* w2   = (const float*)d_in[5];  // [1,32,3,3]
  const float* b2   = (const float*)d_in[6];  // [1]
  float* out = (float*)d_out;                 // [1,1,256,256]

  float* ws = (float*)d_ws;
  __half* y2h = (__half*)ws;                         // [400][32][512] f16 = 13.1 MB
  float* vol  = ws + (A_ANG * CCH * DDET) / 2;       // [256][256][32] f32 = 8.4 MB
  float* sig1 = vol + NVOL * NVOL * CCH;             // [256][256][32] f32 = 8.4 MB

  // detconv also zeroes vol (memset node folded in; 4 graph nodes total)
  k_detconv<<<dim3((A_ANG * CCH * DDET / 2) / 256), dim3(256), 0, stream>>>(
      x, wdet, bdet, y2h, vol);
  k_backproj<<<dim3(256 * NCHUNK), dim3(256), 0, stream>>>(y2h, vol);
  k_conv1<<<dim3(256 * 4), dim3(256), 0, stream>>>(vol, w1, b1, sig1);
  k_conv2<<<dim3(256 * 4), dim3(256), 0, stream>>>(sig1, w2, b2, out);
}

// Round 20
// 145.152 us; speedup vs baseline: 1.7684x; 1.0967x over previous
//
#include <hip/hip_runtime.h>
#include <hip/hip_fp16.h>
#include <math.h>
#include <stdint.h>

#define A_ANG 400
#define DDET  512
#define NVOL  256
#define CCH   32
#define KSZ   11
#define PI_F  3.14159265358979323846f

#define NCHUNK 5
#define APC (A_ANG / NCHUNK)   // 80 angles per block

typedef _Float16 half8 __attribute__((ext_vector_type(8)));
typedef __fp16  fp16x2 __attribute__((ext_vector_type(2)));  // cvt_pkrtz ret type
typedef float   floatx4 __attribute__((ext_vector_type(4)));
typedef uint32_t u32x4a __attribute__((ext_vector_type(4), aligned(4)));

// ---------------------------------------------------------------------------
// K1: causal detector conv -> f16 CHANNEL-MAJOR y[a][c][d] (packed half2).
// Also zeroes vol (memset graph node folded in).
// ---------------------------------------------------------------------------
__global__ __launch_bounds__(256) void k_detconv(const float* __restrict__ x,
                                                 const float* __restrict__ wdet,
                                                 const float* __restrict__ bdet,
                                                 __half* __restrict__ y2h,
                                                 float* __restrict__ vol) {
  __shared__ float wl[CCH * KSZ];
  __shared__ float bl[CCH];
  int t = threadIdx.x;
  for (int e = t; e < CCH * KSZ; e += 256) wl[e] = wdet[e];
  if (t < CCH) bl[t] = bdet[t];
  __syncthreads();

  int idx = blockIdx.x * 256 + t;  // = a*8192 + c*256 + d2
  if (idx < NVOL * NVOL * CCH) vol[idx] = 0.0f;  // zero vol for atomics
  int d2 = idx & 255;
  int c = (idx >> 8) & 31;
  int a = idx >> 13;
  const float* xr = x + a * DDET;
  int d0 = 2 * d2;
  float acc0 = bl[c], acc1 = bl[c];
#pragma unroll
  for (int k = 0; k < KSZ; ++k) {
    float wv = wl[c * KSZ + k];
    int dd0 = d0 + k - (KSZ - 1);
    int dd1 = dd0 + 1;
    float xv0 = (dd0 >= 0) ? xr[dd0] : 0.0f;
    float xv1 = (dd1 >= 0) ? xr[dd1] : 0.0f;
    acc0 = fmaf(wv, xv0, acc0);
    acc1 = fmaf(wv, xv1, acc1);
  }
  __half2 hv = __floats2half2_rn(acc0, acc1);
  *reinterpret_cast<__half2*>(y2h + ((size_t)(a * CCH + c) * DDET + d0)) = hv;
}

// ---------------------------------------------------------------------------
// K2: backprojection v13 (BYTE-REVERT to R17 — session best: 79.0 µs).
// Occupancy lever refuted: NCHUNK=8 at VGPR=40 (R19) = 92 µs — atomic
// traffic, epilogue repetitions, and bank conflicts scale with NCHUNK
// faster than latency-hiding gains.  NCHUNK=5 is the measured optimum.
// B-fragments direct from L2 (no LDS staging), 2-pair register pipeline.
// ---------------------------------------------------------------------------
__global__ __launch_bounds__(256, 4) void k_backproj(const __half* __restrict__ y2h,
                                                     float* __restrict__ vol) {
  __shared__ float s_epi[16 * 257];  // epilogue transpose (16.4 KB)
  __shared__ float s_sin[APC];
  __shared__ float s_cos[APC];

  int t = threadIdx.x;
  int lane = t & 63;
  int w = t >> 6;        // wave id 0..3
  int h = lane >> 4;     // k-group 0..3: angle ga=h>>1, cell-half hh=h&1
  int r = lane & 15;     // A-row / B,D-col index

  int tile = blockIdx.x & 255;
  int chunk = blockIdx.x >> 8;   // 0..NCHUNK-1 (grid = 256*NCHUNK)
  int a0 = chunk * APC;

  for (int a = t; a < APC; a += 256) {
    float ph = ((float)(a0 + a) + 0.5f) * (PI_F / (float)A_ANG);
    float sv, cv;
    sincosf(ph, &sv, &cv);
    s_sin[a] = sv;
    s_cos[a] = cv;
  }

  int bi = tile >> 4, bj = tile & 15;
  int wi = w >> 1, wj = w & 1;   // wave-tile position (2x2 of 8x8)
  int hh = h & 1;
  int ga = h >> 1;
  float Xcw = 124.0f - (float)(bi * 16 + 8 * wi);        // 127.5-(base+3.5)
  float Ycw = (float)(bj * 16 + 8 * wj) - 124.0f;
  float Xlh = 127.5f - (float)(bi * 16 + 8 * wi + 4 * hh + (r >> 3));
  float Yl  = (float)(bj * 16 + 8 * wj + (r & 7)) - 127.5f;

  int bpaA = (((h & 2) | 0) * 16 + r) << 2;
  int bpaB = (((h & 2) | 1) * 16 + r) << 2;

  const uint32_t* y2a = (const uint32_t*)y2h + (size_t)a0 * 8192;
  // per-lane invariant part of the window address (u32 units)
  int choff = r * 256 + 4 * hh;

  floatx4 acc[4][2];
#pragma unroll
  for (int m = 0; m < 4; ++m)
#pragma unroll
    for (int n = 0; n < 2; ++n) acc[m][n] = (floatx4){0.f, 0.f, 0.f, 0.f};

  __syncthreads();  // sin/cos tables ready

  union bfrag { u32x4a u4; half8 v; };

  // load this lane's 2 B-fragments for pair k (angle k+ga) straight from L2
  auto loadPair = [&](int k, bfrag& b0, bfrag& b1) {
    int ak = k + ga;
    ak = (ak < APC) ? ak : (APC - 1);   // tail prefetch clamp (data unused)
    float sp = s_sin[ak], cp = s_cos[ak];
    float ucw = fmaf(Xcw, sp, fmaf(Ycw, cp, 255.5f));
    int ibw = ((int)floorf(ucw) - 7) & ~1;
    const uint32_t* p = y2a + ak * 8192 + choff + (ibw >> 1);
    b0.u4 = *(const u32x4a*)p;          // ch r,    cells ibw+8hh..+7
    b1.u4 = *(const u32x4a*)(p + 4096); // ch 16+r, same cells
  };

  auto computePair = [&](int k, bfrag b0, bfrag b1) {
    int ak = k + ga;                  // lane's packed angle
    float sp = s_sin[ak], cp = s_cos[ak];
    float ucw = fmaf(Xcw, sp, fmaf(Ycw, cp, 255.5f));
    int ibw = ((int)floorf(ucw) - 7) & ~1;   // identical to load-time value
    uint32_t lov[2], msgv[2];
    float us = fmaf(Xlh, sp, fmaf(Yl, cp, 255.5f));
#pragma unroll
    for (int cch = 0; cch < 2; ++cch) {
      float fl = floorf(us);
      float wf = us - fl;
      int e = (int)fl - ibw;           // provably [2,13]
      float w0 = 1.0f - wf;
      union { fp16x2 hv; uint32_t u; } p01;
      p01.hv = __builtin_amdgcn_cvt_pkrtz(w0, wf);   // (w0,w1)
      // 64-bit shift trick: (lo,hi) = p01 << (16*(e&1))
      uint64_t v64 = ((uint64_t)p01.u) << ((e & 1) << 4);
      lov[cch] = (uint32_t)v64;
      msgv[cch] = (uint32_t)(v64 >> 32) | ((uint32_t)(e >> 1) << 16);
      us = fmaf(-2.0f, sp, us);  // next owned row (i += 2)
    }
    __builtin_amdgcn_s_setprio(1);
#pragma unroll
    for (int m = 0; m < 4; ++m) {
      int bpa = (m < 2) ? bpaA : bpaB;
      uint32_t lom =
          (uint32_t)__builtin_amdgcn_ds_bpermute(bpa, (int)((m & 1) ? lov[1] : lov[0]));
      uint32_t mm =
          (uint32_t)__builtin_amdgcn_ds_bpermute(bpa, (int)((m & 1) ? msgv[1] : msgv[0]));
      int qm = (int)(mm >> 16) - 4 * hh;
      uint32_t him = mm & 0xFFFFu;
      union { uint32_t u[4]; half8 v; } af;
#pragma unroll
      for (int j2 = 0; j2 < 4; ++j2) {
        uint32_t rj = (qm == j2) ? lom : 0u;
        rj = (qm == j2 - 1) ? him : rj;
        af.u[j2] = rj;
      }
      acc[m][0] =
          __builtin_amdgcn_mfma_f32_16x16x32_f16(af.v, b0.v, acc[m][0], 0, 0, 0);
      acc[m][1] =
          __builtin_amdgcn_mfma_f32_16x16x32_f16(af.v, b1.v, acc[m][1], 0, 0, 0);
    }
    __builtin_amdgcn_s_setprio(0);
  };

  // 2-pair register pipeline: compute(k,A); refill A<-k+4; compute(k+2,B);
  // refill B<-k+6.  Loads issued one full pair-compute ahead of use.
  bfrag A0, A1, B0, B1;
  loadPair(0, A0, A1);
  loadPair(2, B0, B1);
  for (int k = 0; k < APC; k += 4) {
    computePair(k, A0, A1);
    loadPair(k + 4, A0, A1);
    computePair(k + 2, B0, B1);
    loadPair(k + 6, B0, B1);
  }

  __syncthreads();  // all waves done accumulating before epilogue writes

  const float DPHI = PI_F / (float)A_ANG;
  size_t gbase = ((size_t)(bi * 16) * NVOL + (size_t)(bj * 16)) * CCH;
#pragma unroll
  for (int n = 0; n < 2; ++n) {
    if (n) __syncthreads();  // pass-0 reads done before overwrite
#pragma unroll
    for (int m = 0; m < 4; ++m)
#pragma unroll
      for (int jr = 0; jr < 4; ++jr) {
        int p = 4 * h + jr;
        int px = (8 * wi + 2 * m + (p >> 3)) * 16 + 8 * wj + (p & 7);
        s_epi[r * 257 + px] = acc[m][n][jr] * DPHI;
      }
    __syncthreads();
#pragma unroll
    for (int mm = 0; mm < 16; ++mm) {
      int f = mm * 256 + t;
      int c16 = f & 15;
      int p2 = f >> 4;  // pixel 0..255
      int jj = p2 & 15, ii = p2 >> 4;
      float v = s_epi[c16 * 257 + p2];
      atomicAdd(vol + gbase + ((size_t)ii * NVOL + jj) * CCH + 16 * n + c16, v);
    }
  }
}

// ---------------------------------------------------------------------------
// K3: 3x3 causal conv 32->32 + sigmoid, MFMA formulation (unchanged, R17).
// ---------------------------------------------------------------------------
__global__ __launch_bounds__(256) void k_conv1(const float* __restrict__ vol,
                                               const float* __restrict__ w1,
                                               const float* __restrict__ b1,
                                               float* __restrict__ out1) {
  __shared__ uint32_t wlds[9 * 2 * 256];  // 18KB: [p][n][lane*4+q] f16-pairs
  int t = threadIdx.x;
  for (int u = t; u < 9 * 2 * 256; u += 256) {
    int q = u & 3;
    int lane_s = (u >> 2) & 63;
    int blk = u >> 8;          // 0..17
    int p = blk >> 1, n = blk & 1;
    int hs = lane_s >> 4, rs = lane_s & 15;
    int oc = 16 * n + rs;
    int ci0 = 8 * hs + 2 * q;
    int di = p / 3, dj = p % 3;
    float a0 = w1[((oc * CCH + ci0) * 3 + di) * 3 + dj];
    float a1 = w1[((oc * CCH + ci0 + 1) * 3 + di) * 3 + dj];
    union { fp16x2 hv; uint32_t u32; } pk;
    pk.hv = __builtin_amdgcn_cvt_pkrtz(a0, a1);
    wlds[u] = pk.u32;
  }
  __syncthreads();

  int lane = t & 63;
  int w = t >> 6;
  int h = lane >> 4, r = lane & 15;
  int px0 = (blockIdx.x * 4 + w) * 16;  // 16-aligned -> single image row
  int i = px0 >> 8, j0 = px0 & 255;

  floatx4 acc[2];
  float bv0 = b1[r], bv1 = b1[16 + r];
  acc[0] = (floatx4){bv0, bv0, bv0, bv0};
  acc[1] = (floatx4){bv1, bv1, bv1, bv1};

#pragma unroll
  for (int p = 0; p < 9; ++p) {
    int di = p / 3, dj = p % 3;
    int ii = i + di - 2;
    if (ii >= 0) {                       // wave-uniform causal row skip
      int jrp = j0 + r + dj - 2;         // A-row r's source column
      int jc = max(jrp, 0);
      const float4* ap =
          (const float4*)(vol + ((size_t)(ii * NVOL + jc)) * CCH + 8 * h);
      float4 v0 = ap[0], v1 = ap[1];
      if (jrp < 0) {                     // zero-pad (only j0=0, r<2, dj<2)
        v0 = (float4){0.f, 0.f, 0.f, 0.f};
        v1 = (float4){0.f, 0.f, 0.f, 0.f};
      }
      union { uint32_t u[4]; half8 v; } af;
      union { fp16x2 hv; uint32_t u32; } c0, c1, c2, c3;
      c0.hv = __builtin_amdgcn_cvt_pkrtz(v0.x, v0.y);
      c1.hv = __builtin_amdgcn_cvt_pkrtz(v0.z, v0.w);
      c2.hv = __builtin_amdgcn_cvt_pkrtz(v1.x, v1.y);
      c3.hv = __builtin_amdgcn_cvt_pkrtz(v1.z, v1.w);
      af.u[0] = c0.u32; af.u[1] = c1.u32; af.u[2] = c2.u32; af.u[3] = c3.u32;
      half8 bf0 = *(const half8*)(wlds + (p * 2 + 0) * 256 + lane * 4);
      half8 bf1 = *(const half8*)(wlds + (p * 2 + 1) * 256 + lane * 4);
      acc[0] = __builtin_amdgcn_mfma_f32_16x16x32_f16(af.v, bf0, acc[0], 0, 0, 0);
      acc[1] = __builtin_amdgcn_mfma_f32_16x16x32_f16(af.v, bf1, acc[1], 0, 0, 0);
    }
  }

  // D: lane holds pixels px0+4h+jr, oc = 16n+r
#pragma unroll
  for (int n = 0; n < 2; ++n)
#pragma unroll
    for (int jr = 0; jr < 4; ++jr) {
      float s = 1.0f / (1.0f + expf(-acc[n][jr]));
      out1[(size_t)(px0 + 4 * h + jr) * CCH + 16 * n + r] = s;
    }
}

// ---------------------------------------------------------------------------
// K4: 3x3 causal conv 32->1 + sigmoid, coalesced lane mapping (unchanged).
// ---------------------------------------------------------------------------
__global__ __launch_bounds__(256) void k_conv2(const float* __restrict__ s1,
                                               const float* __restrict__ w2,
                                               const float* __restrict__ b2,
                                               float* __restrict__ out) {
  __shared__ float wl[9 * CCH];  // [p][ci]
  __shared__ float red[256];
  int t = threadIdx.x;
  for (int e = t; e < 9 * CCH; e += 256) {
    int ci = e & 31, p = e >> 5;
    int di = p / 3, dj = p % 3;
    wl[e] = w2[ci * 9 + di * 3 + dj];
  }
  __syncthreads();

  int px0 = blockIdx.x * 64;
  int pix = px0 + (t >> 2);        // coalesced: 4 consecutive lanes = 1 px
  int j = pix & 255, i = pix >> 8;
  int cg = (t & 3) * 8;            // this thread's 8 input channels

  float acc = 0.0f;
#pragma unroll
  for (int p = 0; p < 9; ++p) {
    int di = p / 3, dj = p % 3;
    int ii = i + di - 2, jj = j + dj - 2;
    if (ii >= 0 && jj >= 0) {
      const float4* ip4 =
          (const float4*)(s1 + ((size_t)(ii * NVOL + jj)) * CCH + cg);
      const float4* wv4 = (const float4*)(&wl[p * CCH + cg]);
      float4 v0 = ip4[0], v1 = ip4[1];
      float4 w0 = wv4[0], w1 = wv4[1];
      acc = fmaf(v0.x, w0.x, acc);
      acc = fmaf(v0.y, w0.y, acc);
      acc = fmaf(v0.z, w0.z, acc);
      acc = fmaf(v0.w, w0.w, acc);
      acc = fmaf(v1.x, w1.x, acc);
      acc = fmaf(v1.y, w1.y, acc);
      acc = fmaf(v1.z, w1.z, acc);
      acc = fmaf(v1.w, w1.w, acc);
    }
  }
  red[t] = acc;
  __syncthreads();
  if (t < 64) {
    float4 rv = *(const float4*)(&red[4 * t]);
    float s = rv.x + rv.y + rv.z + rv.w + b2[0];
    out[px0 + t] = 1.0f / (1.0f + expf(-s));
  }
}

// ---------------------------------------------------------------------------
extern "C" void kernel_launch(void* const* d_in, const int* in_sizes, int n_in,
                              void* d_out, int out_size, void* d_ws,
                              size_t ws_size, hipStream_t stream) {
  const float* x    = (const float*)d_in[0];  // [1,1,400,512]
  const float* wdet = (const float*)d_in[1];  // [32,1,1,11]
  const float* bdet = (const float*)d_in[2];  // [32]
  const float* w1   = (const float*)d_in[3];  // [32,32,3,3]
  const float* b1   = (const float*)d_in[4];  // [32]
  const float* w2   = (const float*)d_in[5];  // [1,32,3,3]
  const float* b2   = (const float*)d_in[6];  // [1]
  float* out = (float*)d_out;                 // [1,1,256,256]

  float* ws = (float*)d_ws;
  __half* y2h = (__half*)ws;                         // [400][32][512] f16 = 13.1 MB
  float* vol  = ws + (A_ANG * CCH * DDET) / 2;       // [256][256][32] f32 = 8.4 MB
  float* sig1 = vol + NVOL * NVOL * CCH;             // [256][256][32] f32 = 8.4 MB

  // detconv also zeroes vol (memset node folded in; 4 graph nodes total)
  k_detconv<<<dim3((A_ANG * CCH * DDET / 2) / 256), dim3(256), 0, stream>>>(
      x, wdet, bdet, y2h, vol);
  k_backproj<<<dim3(256 * NCHUNK), dim3(256), 0, stream>>>(y2h, vol);
  k_conv1<<<dim3(256 * 4), dim3(256), 0, stream>>>(vol, w1, b1, sig1);
  k_conv2<<<dim3(256 * 4), dim3(256), 0, stream>>>(sig1, w2, b2, out);
}

// Round 21
// 119.478 us; speedup vs baseline: 2.1484x; 1.2149x over previous
//
#include <hip/hip_runtime.h>
#include <hip/hip_fp16.h>
#include <math.h>
#include <stdint.h>

#define A_ANG 400
#define DDET  512
#define NVOL  256
#define CCH   32
#define KSZ   11
#define PI_F  3.14159265358979323846f

#define NCHUNK 5
#define APC (A_ANG / NCHUNK)   // 80 angles per block

typedef _Float16 half8 __attribute__((ext_vector_type(8)));
typedef __fp16  fp16x2 __attribute__((ext_vector_type(2)));  // cvt_pkrtz ret type
typedef float   floatx4 __attribute__((ext_vector_type(4)));
typedef uint32_t u32x4a __attribute__((ext_vector_type(4), aligned(4)));

// ---------------------------------------------------------------------------
// K1: causal detector conv -> f16 CHANNEL-MAJOR y[a][c][d], v2.
// 8 outputs/thread: grid 12800 -> 3200 blocks; hoisted 18-float x-window
// (18 loads + 88 FMA, full ILP); one 16B half8 store (was 4B half2).
// Also zeroes vol via float4 stores (memset node stays folded in).
// ---------------------------------------------------------------------------
__global__ __launch_bounds__(256) void k_detconv(const float* __restrict__ x,
                                                 const float* __restrict__ wdet,
                                                 const float* __restrict__ bdet,
                                                 __half* __restrict__ y2h,
                                                 float* __restrict__ vol) {
  __shared__ float wl[CCH * KSZ];
  __shared__ float bl[CCH];
  int t = threadIdx.x;
  for (int e = t; e < CCH * KSZ; e += 256) wl[e] = wdet[e];
  if (t < CCH) bl[t] = bdet[t];
  __syncthreads();

  int idx = blockIdx.x * 256 + t;  // = a*2048 + c*64 + d8  (819200 total)
  if (idx < (NVOL * NVOL * CCH) / 4) {
    ((float4*)vol)[idx] = (float4){0.f, 0.f, 0.f, 0.f};  // zero vol
  }
  int d8 = idx & 63;
  int c = (idx >> 6) & 31;   // wave-uniform (64 threads span one c)
  int a = idx >> 11;
  const float* xr = x + a * DDET;
  int d0 = 8 * d8;

  // hoisted input window: dd = d0-10 .. d0+7 (18 values, zero-pad left)
  float xv[18];
#pragma unroll
  for (int i2 = 0; i2 < 18; ++i2) {
    int dd = d0 - 10 + i2;
    xv[i2] = (dd >= 0) ? xr[dd] : 0.0f;
  }

  float acc[8];
#pragma unroll
  for (int q = 0; q < 8; ++q) acc[q] = bl[c];
#pragma unroll
  for (int k = 0; k < KSZ; ++k) {
    float wv = wl[c * KSZ + k];
#pragma unroll
    for (int q = 0; q < 8; ++q) acc[q] = fmaf(wv, xv[k + q], acc[q]);
  }

  union { __half2 h2[4]; float4 f4; } ov;
#pragma unroll
  for (int q = 0; q < 4; ++q)
    ov.h2[q] = __floats2half2_rn(acc[2 * q], acc[2 * q + 1]);
  *reinterpret_cast<float4*>(y2h + ((size_t)(a * CCH + c) * DDET + d0)) = ov.f4;
}

// ---------------------------------------------------------------------------
// K2: backprojection v13 (unchanged — session best 79.0 µs; NCHUNK=5 is the
// measured optimum; B-fragments direct from L2, 2-pair register pipeline).
// ---------------------------------------------------------------------------
__global__ __launch_bounds__(256, 4) void k_backproj(const __half* __restrict__ y2h,
                                                     float* __restrict__ vol) {
  __shared__ float s_epi[16 * 257];  // epilogue transpose (16.4 KB)
  __shared__ float s_sin[APC];
  __shared__ float s_cos[APC];

  int t = threadIdx.x;
  int lane = t & 63;
  int w = t >> 6;        // wave id 0..3
  int h = lane >> 4;     // k-group 0..3: angle ga=h>>1, cell-half hh=h&1
  int r = lane & 15;     // A-row / B,D-col index

  int tile = blockIdx.x & 255;
  int chunk = blockIdx.x >> 8;   // 0..NCHUNK-1 (grid = 256*NCHUNK)
  int a0 = chunk * APC;

  for (int a = t; a < APC; a += 256) {
    float ph = ((float)(a0 + a) + 0.5f) * (PI_F / (float)A_ANG);
    float sv, cv;
    sincosf(ph, &sv, &cv);
    s_sin[a] = sv;
    s_cos[a] = cv;
  }

  int bi = tile >> 4, bj = tile & 15;
  int wi = w >> 1, wj = w & 1;   // wave-tile position (2x2 of 8x8)
  int hh = h & 1;
  int ga = h >> 1;
  float Xcw = 124.0f - (float)(bi * 16 + 8 * wi);        // 127.5-(base+3.5)
  float Ycw = (float)(bj * 16 + 8 * wj) - 124.0f;
  float Xlh = 127.5f - (float)(bi * 16 + 8 * wi + 4 * hh + (r >> 3));
  float Yl  = (float)(bj * 16 + 8 * wj + (r & 7)) - 127.5f;

  int bpaA = (((h & 2) | 0) * 16 + r) << 2;
  int bpaB = (((h & 2) | 1) * 16 + r) << 2;

  const uint32_t* y2a = (const uint32_t*)y2h + (size_t)a0 * 8192;
  // per-lane invariant part of the window address (u32 units)
  int choff = r * 256 + 4 * hh;

  floatx4 acc[4][2];
#pragma unroll
  for (int m = 0; m < 4; ++m)
#pragma unroll
    for (int n = 0; n < 2; ++n) acc[m][n] = (floatx4){0.f, 0.f, 0.f, 0.f};

  __syncthreads();  // sin/cos tables ready

  union bfrag { u32x4a u4; half8 v; };

  // load this lane's 2 B-fragments for pair k (angle k+ga) straight from L2
  auto loadPair = [&](int k, bfrag& b0, bfrag& b1) {
    int ak = k + ga;
    ak = (ak < APC) ? ak : (APC - 1);   // tail prefetch clamp (data unused)
    float sp = s_sin[ak], cp = s_cos[ak];
    float ucw = fmaf(Xcw, sp, fmaf(Ycw, cp, 255.5f));
    int ibw = ((int)floorf(ucw) - 7) & ~1;
    const uint32_t* p = y2a + ak * 8192 + choff + (ibw >> 1);
    b0.u4 = *(const u32x4a*)p;          // ch r,    cells ibw+8hh..+7
    b1.u4 = *(const u32x4a*)(p + 4096); // ch 16+r, same cells
  };

  auto computePair = [&](int k, bfrag b0, bfrag b1) {
    int ak = k + ga;                  // lane's packed angle
    float sp = s_sin[ak], cp = s_cos[ak];
    float ucw = fmaf(Xcw, sp, fmaf(Ycw, cp, 255.5f));
    int ibw = ((int)floorf(ucw) - 7) & ~1;   // identical to load-time value
    uint32_t lov[2], msgv[2];
    float us = fmaf(Xlh, sp, fmaf(Yl, cp, 255.5f));
#pragma unroll
    for (int cch = 0; cch < 2; ++cch) {
      float fl = floorf(us);
      float wf = us - fl;
      int e = (int)fl - ibw;           // provably [2,13]
      float w0 = 1.0f - wf;
      union { fp16x2 hv; uint32_t u; } p01;
      p01.hv = __builtin_amdgcn_cvt_pkrtz(w0, wf);   // (w0,w1)
      // 64-bit shift trick: (lo,hi) = p01 << (16*(e&1))
      uint64_t v64 = ((uint64_t)p01.u) << ((e & 1) << 4);
      lov[cch] = (uint32_t)v64;
      msgv[cch] = (uint32_t)(v64 >> 32) | ((uint32_t)(e >> 1) << 16);
      us = fmaf(-2.0f, sp, us);  // next owned row (i += 2)
    }
    __builtin_amdgcn_s_setprio(1);
#pragma unroll
    for (int m = 0; m < 4; ++m) {
      int bpa = (m < 2) ? bpaA : bpaB;
      uint32_t lom =
          (uint32_t)__builtin_amdgcn_ds_bpermute(bpa, (int)((m & 1) ? lov[1] : lov[0]));
      uint32_t mm =
          (uint32_t)__builtin_amdgcn_ds_bpermute(bpa, (int)((m & 1) ? msgv[1] : msgv[0]));
      int qm = (int)(mm >> 16) - 4 * hh;
      uint32_t him = mm & 0xFFFFu;
      union { uint32_t u[4]; half8 v; } af;
#pragma unroll
      for (int j2 = 0; j2 < 4; ++j2) {
        uint32_t rj = (qm == j2) ? lom : 0u;
        rj = (qm == j2 - 1) ? him : rj;
        af.u[j2] = rj;
      }
      acc[m][0] =
          __builtin_amdgcn_mfma_f32_16x16x32_f16(af.v, b0.v, acc[m][0], 0, 0, 0);
      acc[m][1] =
          __builtin_amdgcn_mfma_f32_16x16x32_f16(af.v, b1.v, acc[m][1], 0, 0, 0);
    }
    __builtin_amdgcn_s_setprio(0);
  };

  // 2-pair register pipeline: compute(k,A); refill A<-k+4; compute(k+2,B);
  // refill B<-k+6.  Loads issued one full pair-compute ahead of use.
  bfrag A0, A1, B0, B1;
  loadPair(0, A0, A1);
  loadPair(2, B0, B1);
  for (int k = 0; k < APC; k += 4) {
    computePair(k, A0, A1);
    loadPair(k + 4, A0, A1);
    computePair(k + 2, B0, B1);
    loadPair(k + 6, B0, B1);
  }

  __syncthreads();  // all waves done accumulating before epilogue writes

  const float DPHI = PI_F / (float)A_ANG;
  size_t gbase = ((size_t)(bi * 16) * NVOL + (size_t)(bj * 16)) * CCH;
#pragma unroll
  for (int n = 0; n < 2; ++n) {
    if (n) __syncthreads();  // pass-0 reads done before overwrite
#pragma unroll
    for (int m = 0; m < 4; ++m)
#pragma unroll
      for (int jr = 0; jr < 4; ++jr) {
        int p = 4 * h + jr;
        int px = (8 * wi + 2 * m + (p >> 3)) * 16 + 8 * wj + (p & 7);
        s_epi[r * 257 + px] = acc[m][n][jr] * DPHI;
      }
    __syncthreads();
#pragma unroll
    for (int mm = 0; mm < 16; ++mm) {
      int f = mm * 256 + t;
      int c16 = f & 15;
      int p2 = f >> 4;  // pixel 0..255
      int jj = p2 & 15, ii = p2 >> 4;
      float v = s_epi[c16 * 257 + p2];
      atomicAdd(vol + gbase + ((size_t)ii * NVOL + jj) * CCH + 16 * n + c16, v);
    }
  }
}

// ---------------------------------------------------------------------------
// K3: 3x3 causal conv 32->32 + sigmoid, MFMA formulation, v2: 1024-thread
// blocks (grid 256).  Weight staging (36 scalar w1 loads + cvt + ds_write
// per thread) now runs once per 16 waves instead of once per 4 — 3/4 of
// the 36 MB L2 scalar-gather staging traffic deleted.  Compute body
// identical (w = t>>6 now 0..15; block covers one full image row).
// ---------------------------------------------------------------------------
__global__ __launch_bounds__(1024) void k_conv1(const float* __restrict__ vol,
                                                const float* __restrict__ w1,
                                                const float* __restrict__ b1,
                                                float* __restrict__ out1) {
  __shared__ uint32_t wlds[9 * 2 * 256];  // 18KB: [p][n][lane*4+q] f16-pairs
  int t = threadIdx.x;
  for (int u = t; u < 9 * 2 * 256; u += 1024) {
    int q = u & 3;
    int lane_s = (u >> 2) & 63;
    int blk = u >> 8;          // 0..17
    int p = blk >> 1, n = blk & 1;
    int hs = lane_s >> 4, rs = lane_s & 15;
    int oc = 16 * n + rs;
    int ci0 = 8 * hs + 2 * q;
    int di = p / 3, dj = p % 3;
    float a0 = w1[((oc * CCH + ci0) * 3 + di) * 3 + dj];
    float a1 = w1[((oc * CCH + ci0 + 1) * 3 + di) * 3 + dj];
    union { fp16x2 hv; uint32_t u32; } pk;
    pk.hv = __builtin_amdgcn_cvt_pkrtz(a0, a1);
    wlds[u] = pk.u32;
  }
  __syncthreads();

  int lane = t & 63;
  int w = t >> 6;                        // 0..15
  int h = lane >> 4, r = lane & 15;
  int px0 = (blockIdx.x * 16 + w) * 16;  // 16-aligned -> single image row
  int i = px0 >> 8, j0 = px0 & 255;

  floatx4 acc[2];
  float bv0 = b1[r], bv1 = b1[16 + r];
  acc[0] = (floatx4){bv0, bv0, bv0, bv0};
  acc[1] = (floatx4){bv1, bv1, bv1, bv1};

#pragma unroll
  for (int p = 0; p < 9; ++p) {
    int di = p / 3, dj = p % 3;
    int ii = i + di - 2;
    if (ii >= 0) {                       // wave-uniform causal row skip
      int jrp = j0 + r + dj - 2;         // A-row r's source column
      int jc = max(jrp, 0);
      const float4* ap =
          (const float4*)(vol + ((size_t)(ii * NVOL + jc)) * CCH + 8 * h);
      float4 v0 = ap[0], v1 = ap[1];
      if (jrp < 0) {                     // zero-pad (only j0=0, r<2, dj<2)
        v0 = (float4){0.f, 0.f, 0.f, 0.f};
        v1 = (float4){0.f, 0.f, 0.f, 0.f};
      }
      union { uint32_t u[4]; half8 v; } af;
      union { fp16x2 hv; uint32_t u32; } c0, c1, c2, c3;
      c0.hv = __builtin_amdgcn_cvt_pkrtz(v0.x, v0.y);
      c1.hv = __builtin_amdgcn_cvt_pkrtz(v0.z, v0.w);
      c2.hv = __builtin_amdgcn_cvt_pkrtz(v1.x, v1.y);
      c3.hv = __builtin_amdgcn_cvt_pkrtz(v1.z, v1.w);
      af.u[0] = c0.u32; af.u[1] = c1.u32; af.u[2] = c2.u32; af.u[3] = c3.u32;
      half8 bf0 = *(const half8*)(wlds + (p * 2 + 0) * 256 + lane * 4);
      half8 bf1 = *(const half8*)(wlds + (p * 2 + 1) * 256 + lane * 4);
      acc[0] = __builtin_amdgcn_mfma_f32_16x16x32_f16(af.v, bf0, acc[0], 0, 0, 0);
      acc[1] = __builtin_amdgcn_mfma_f32_16x16x32_f16(af.v, bf1, acc[1], 0, 0, 0);
    }
  }

  // D: lane holds pixels px0+4h+jr, oc = 16n+r
#pragma unroll
  for (int n = 0; n < 2; ++n)
#pragma unroll
    for (int jr = 0; jr < 4; ++jr) {
      float s = 1.0f / (1.0f + expf(-acc[n][jr]));
      out1[(size_t)(px0 + 4 * h + jr) * CCH + 16 * n + r] = s;
    }
}

// ---------------------------------------------------------------------------
// K4: 3x3 causal conv 32->1 + sigmoid, coalesced lane mapping (unchanged).
// ---------------------------------------------------------------------------
__global__ __launch_bounds__(256) void k_conv2(const float* __restrict__ s1,
                                               const float* __restrict__ w2,
                                               const float* __restrict__ b2,
                                               float* __restrict__ out) {
  __shared__ float wl[9 * CCH];  // [p][ci]
  __shared__ float red[256];
  int t = threadIdx.x;
  for (int e = t; e < 9 * CCH; e += 256) {
    int ci = e & 31, p = e >> 5;
    int di = p / 3, dj = p % 3;
    wl[e] = w2[ci * 9 + di * 3 + dj];
  }
  __syncthreads();

  int px0 = blockIdx.x * 64;
  int pix = px0 + (t >> 2);        // coalesced: 4 consecutive lanes = 1 px
  int j = pix & 255, i = pix >> 8;
  int cg = (t & 3) * 8;            // this thread's 8 input channels

  float acc = 0.0f;
#pragma unroll
  for (int p = 0; p < 9; ++p) {
    int di = p / 3, dj = p % 3;
    int ii = i + di - 2, jj = j + dj - 2;
    if (ii >= 0 && jj >= 0) {
      const float4* ip4 =
          (const float4*)(s1 + ((size_t)(ii * NVOL + jj)) * CCH + cg);
      const float4* wv4 = (const float4*)(&wl[p * CCH + cg]);
      float4 v0 = ip4[0], v1 = ip4[1];
      float4 w0 = wv4[0], w1 = wv4[1];
      acc = fmaf(v0.x, w0.x, acc);
      acc = fmaf(v0.y, w0.y, acc);
      acc = fmaf(v0.z, w0.z, acc);
      acc = fmaf(v0.w, w0.w, acc);
      acc = fmaf(v1.x, w1.x, acc);
      acc = fmaf(v1.y, w1.y, acc);
      acc = fmaf(v1.z, w1.z, acc);
      acc = fmaf(v1.w, w1.w, acc);
    }
  }
  red[t] = acc;
  __syncthreads();
  if (t < 64) {
    float4 rv = *(const float4*)(&red[4 * t]);
    float s = rv.x + rv.y + rv.z + rv.w + b2[0];
    out[px0 + t] = 1.0f / (1.0f + expf(-s));
  }
}

// ---------------------------------------------------------------------------
extern "C" void kernel_launch(void* const* d_in, const int* in_sizes, int n_in,
                              void* d_out, int out_size, void* d_ws,
                              size_t ws_size, hipStream_t stream) {
  const float* x    = (const float*)d_in[0];  // [1,1,400,512]
  const float* wdet = (const float*)d_in[1];  // [32,1,1,11]
  const float* bdet = (const float*)d_in[2];  // [32]
  const float* w1   = (const float*)d_in[3];  // [32,32,3,3]
  const float* b1   = (const float*)d_in[4];  // [32]
  const float* w2   = (const float*)d_in[5];  // [1,32,3,3]
  const float* b2   = (const float*)d_in[6];  // [1]
  float* out = (float*)d_out;                 // [1,1,256,256]

  float* ws = (float*)d_ws;
  __half* y2h = (__half*)ws;                         // [400][32][512] f16 = 13.1 MB
  float* vol  = ws + (A_ANG * CCH * DDET) / 2;       // [256][256][32] f32 = 8.4 MB
  float* sig1 = vol + NVOL * NVOL * CCH;             // [256][256][32] f32 = 8.4 MB

  // detconv also zeroes vol (memset node folded in; 4 graph nodes total)
  k_detconv<<<dim3((A_ANG * CCH * DDET / 8) / 256), dim3(256), 0, stream>>>(
      x, wdet, bdet, y2h, vol);
  k_backproj<<<dim3(256 * NCHUNK), dim3(256), 0, stream>>>(y2h, vol);
  k_conv1<<<dim3(256), dim3(1024), 0, stream>>>(vol, w1, b1, sig1);
  k_conv2<<<dim3(256 * 4), dim3(256), 0, stream>>>(sig1, w2, b2, out);
}